// Round 6
// baseline (173.304 us; speedup 1.0000x reference)
//
#include <hip/hip_runtime.h>
#include <math.h>

// Problem constants
#define NB     16
#define HEADS  8
#define HD     64
#define EMBED  512
#define QL     512
#define KL     512

// ws layout (float-unit offsets)
#define WS_QU   0           // bf16 [16][8][512][64]
#define WS_QV   2097152     // bf16 [16][8][512][64]
#define WS_KB   4194304     // bf16 [16][8][512][64]
#define WS_VT   6291456     // bf16 [16][8][64][512]  (v transposed)
#define WS_PEB  8388608     // bf16 [1024][512]
#define WS_RELB 8912896     // bf16 [8][1024][64]
#define WS_OH   9175040     // bf16 [16][512][512]

typedef __attribute__((ext_vector_type(8))) short bf16x8;
typedef __attribute__((ext_vector_type(4))) float f32x4;
typedef __attribute__((ext_vector_type(8))) unsigned short ushort8v;
typedef __attribute__((ext_vector_type(4))) unsigned short ushort4v;

#define MFMA16 __builtin_amdgcn_mfma_f32_16x16x32_bf16

static __device__ __forceinline__ unsigned short f2bf(float x) {
    unsigned u = __builtin_bit_cast(unsigned, x);
    u += 0x7fffu + ((u >> 16) & 1u);      // round-to-nearest-even
    return (unsigned short)(u >> 16);
}

// pack 8 f32 -> bf16x8 via v_cvt_pk_bf16_f32 (RNE), 4 instructions
static __device__ __forceinline__ bf16x8 pack8(f32x4 a, f32x4 b) {
    union { bf16x8 v; unsigned u[4]; } r;
    asm("v_cvt_pk_bf16_f32 %0, %1, %2" : "=v"(r.u[0]) : "v"(a[0]), "v"(a[1]));
    asm("v_cvt_pk_bf16_f32 %0, %1, %2" : "=v"(r.u[1]) : "v"(a[2]), "v"(a[3]));
    asm("v_cvt_pk_bf16_f32 %0, %1, %2" : "=v"(r.u[2]) : "v"(b[0]), "v"(b[1]));
    asm("v_cvt_pk_bf16_f32 %0, %1, %2" : "=v"(r.u[3]) : "v"(b[2]), "v"(b[3]));
    return r.v;
}

// ---------------------------------------------------------------- PE table (bf16)
__global__ void pe_kernel(unsigned short* __restrict__ peb) {
    int j = blockIdx.x;        // 0..1023
    int i = threadIdx.x;       // 0..255
    float invf = exp2f(-(float)i * (13.287712379549449f / 256.0f));
    float ang  = (float)j * invf;
    peb[j * 512 + i]       = f2bf(sinf(ang));
    peb[j * 512 + 256 + i] = f2bf(cosf(ang));
}

// ----------------------------------------- relb = bf16(PE @ Wr^T), MFMA
// grid 128: bm = blk>>3 (64-row j tile), bn = blk&7 (64-col e tile = head bn)
__global__ __launch_bounds__(256) void rel_kernel(const unsigned short* __restrict__ peb,
                                                  const float* __restrict__ Wr,
                                                  unsigned short* __restrict__ relb) {
    __shared__ __align__(16) unsigned short At[64][64];
    __shared__ __align__(16) unsigned short Bt[64][64];
    int bm = blockIdx.x >> 3, bn = blockIdx.x & 7;
    int tid = threadIdx.x;
    int w = tid >> 6, lane = tid & 63;
    int fr = lane & 15, fg = lane >> 4;
    f32x4 acc[4] = {};
    for (int kk = 0; kk < 512; kk += 64) {
        __syncthreads();
        for (int p = 0; p < 2; ++p) {
            int idx = tid + 256 * p;              // 0..511
            int row = idx >> 3, slot = idx & 7;
            *(bf16x8*)&At[row][((slot ^ (row & 7))) * 8] =
                *(const bf16x8*)&peb[(bm * 64 + row) * 512 + kk + slot * 8];
        }
        for (int p = 0; p < 4; ++p) {
            int idx = tid + 256 * p;              // 0..1023 = 64 rows x 16 float4
            int row = idx >> 4, c4 = idx & 15;
            float4 v = *(const float4*)&Wr[(bn * 64 + row) * 512 + kk + c4 * 4];
            ushort4v pk;
            pk[0] = f2bf(v.x); pk[1] = f2bf(v.y); pk[2] = f2bf(v.z); pk[3] = f2bf(v.w);
            int slot = c4 >> 1, rem = (c4 & 1) * 4;
            *(ushort4v*)&Bt[row][((slot ^ (row & 7))) * 8 + rem] = pk;
        }
        __syncthreads();
        bf16x8 af[2];
        int ar = w * 16 + fr;
#pragma unroll
        for (int s = 0; s < 2; ++s)
            af[s] = *(const bf16x8*)&At[ar][((fg + 4 * s) ^ (ar & 7)) * 8];
#pragma unroll
        for (int c = 0; c < 4; ++c) {
            int br = c * 16 + fr;
#pragma unroll
            for (int s = 0; s < 2; ++s) {
                bf16x8 bf = *(const bf16x8*)&Bt[br][((fg + 4 * s) ^ (br & 7)) * 8];
                acc[c] = MFMA16(af[s], bf, acc[c], 0, 0, 0);
            }
        }
    }
#pragma unroll
    for (int c = 0; c < 4; ++c)
#pragma unroll
        for (int i = 0; i < 4; ++i)
            relb[(bn * 1024 + bm * 64 + w * 16 + fg * 4 + i) * 64 + c * 16 + fr] =
                f2bf(acc[c][i]);
}

// ------------------------------------------------- q/k/v head projections, MFMA
// grid 256: n = blk>>4, t0 = (blk&15)*32; 256 threads = 4 waves; wave w -> heads 2w,2w+1
__global__ __launch_bounds__(256) void proj_kernel(const float* __restrict__ query,
                                                   const float* __restrict__ keys,
                                                   const float* __restrict__ values,
                                                   const float* __restrict__ Wq,
                                                   const float* __restrict__ Wk,
                                                   const float* __restrict__ Wv,
                                                   const float* __restrict__ u_bias,
                                                   const float* __restrict__ v_bias,
                                                   float* __restrict__ ws) {
    __shared__ __align__(16) unsigned short inb[32][512];     // 32 KB
    __shared__ __align__(16) unsigned short Wb[3][64][64];    // 24 KB
    __shared__ __align__(16) unsigned short vtile[4][64][36]; // 18 KB
    int n = blockIdx.x >> 4, t0 = (blockIdx.x & 15) * 32;
    int tid = threadIdx.x;
    int w = tid >> 6, lane = tid & 63;
    int fr = lane & 15, fg = lane >> 4;

    for (int p = 0; p < 3; ++p) {
        const float* Wp = (p == 0) ? Wq : (p == 1) ? Wk : Wv;
        for (int it = 0; it < 4; ++it) {
            int idx = tid + 256 * it;            // 0..1023 = 64 rows x 16 float4
            int row = idx >> 4, c4 = idx & 15;
            float4 v = *(const float4*)&Wp[row * 64 + c4 * 4];
            ushort4v pk;
            pk[0] = f2bf(v.x); pk[1] = f2bf(v.y); pk[2] = f2bf(v.z); pk[3] = f2bf(v.w);
            int slot = c4 >> 1, rem = (c4 & 1) * 4;
            *(ushort4v*)&Wb[p][row][((slot ^ (row & 7))) * 8 + rem] = pk;
        }
    }
    unsigned short* qu_b = (unsigned short*)(ws + WS_QU);
    unsigned short* qv_b = (unsigned short*)(ws + WS_QV);
    unsigned short* k_b  = (unsigned short*)(ws + WS_KB);
    unsigned short* vT_b = (unsigned short*)(ws + WS_VT);

    for (int p = 0; p < 3; ++p) {
        const float* src = (p == 0) ? query : (p == 1) ? keys : values;
        __syncthreads();                         // Wb ready / inb WAR
        for (int it = 0; it < 16; ++it) {
            int idx = tid + 256 * it;            // 0..4095 = 32 rows x 128 float4
            int row = idx >> 7, c4 = idx & 127;
            float4 v = *(const float4*)&src[((long)(n * 512 + t0 + row)) * 512 + c4 * 4];
            ushort4v pk;
            pk[0] = f2bf(v.x); pk[1] = f2bf(v.y); pk[2] = f2bf(v.z); pk[3] = f2bf(v.w);
            int slot = c4 >> 1, rem = (c4 & 1) * 4;
            *(ushort4v*)&inb[row][((slot ^ (row & 7))) * 8 + rem] = pk;
        }
        __syncthreads();
        for (int hh = 0; hh < 2; ++hh) {
            int h = w * 2 + hh, nh = n * 8 + h;
            bf16x8 af[2][2];
#pragma unroll
            for (int tt = 0; tt < 2; ++tt) {
                int ar = tt * 16 + fr;
#pragma unroll
                for (int s = 0; s < 2; ++s)
                    af[tt][s] = *(const bf16x8*)&inb[ar][(h * 8 + ((fg + 4 * s) ^ (ar & 7))) * 8];
            }
            f32x4 acc[2][4] = {};
#pragma unroll
            for (int dt = 0; dt < 4; ++dt) {
                int br = dt * 16 + fr;
                bf16x8 bf[2];
#pragma unroll
                for (int s = 0; s < 2; ++s)
                    bf[s] = *(const bf16x8*)&Wb[p][br][((fg + 4 * s) ^ (br & 7)) * 8];
#pragma unroll
                for (int tt = 0; tt < 2; ++tt)
#pragma unroll
                    for (int s = 0; s < 2; ++s)
                        acc[tt][dt] = MFMA16(af[tt][s], bf[s], acc[tt][dt], 0, 0, 0);
            }
            if (p == 0) {
#pragma unroll
                for (int dt = 0; dt < 4; ++dt) {
                    float ub = u_bias[h * 64 + dt * 16 + fr];
                    float vb = v_bias[h * 64 + dt * 16 + fr];
#pragma unroll
                    for (int tt = 0; tt < 2; ++tt)
#pragma unroll
                        for (int i = 0; i < 4; ++i) {
                            long o = ((long)(nh * 512 + t0 + tt * 16 + fg * 4 + i)) * 64 +
                                     dt * 16 + fr;
                            qu_b[o] = f2bf(acc[tt][dt][i] + ub);
                            qv_b[o] = f2bf(acc[tt][dt][i] + vb);
                        }
                }
            } else if (p == 1) {
#pragma unroll
                for (int dt = 0; dt < 4; ++dt)
#pragma unroll
                    for (int tt = 0; tt < 2; ++tt)
#pragma unroll
                        for (int i = 0; i < 4; ++i)
                            k_b[((long)(nh * 512 + t0 + tt * 16 + fg * 4 + i)) * 64 +
                                dt * 16 + fr] = f2bf(acc[tt][dt][i]);
            } else {
                // transpose via per-wave LDS tile, then coalesced vT store
#pragma unroll
                for (int dt = 0; dt < 4; ++dt)
#pragma unroll
                    for (int tt = 0; tt < 2; ++tt)
#pragma unroll
                        for (int i = 0; i < 4; ++i)
                            vtile[w][dt * 16 + fr][tt * 16 + fg * 4 + i] =
                                f2bf(acc[tt][dt][i]);
                __syncthreads();
#pragma unroll
                for (int dg = 0; dg < 8; ++dg) {
                    int d = dg * 8 + (lane >> 3), tq = lane & 7;
                    *(ushort4v*)&vT_b[((long)(nh * 64 + d)) * 512 + t0 + tq * 4] =
                        *(const ushort4v*)&vtile[w][d][tq * 4];
                }
                __syncthreads();
            }
        }
    }
}

// ------------------------------------------- fused MFMA scores+softmax+PV
// one block per (n, h, q-tile of 16); 512 threads = 8 waves; 4 blocks/CU
// XCD swizzle: blocks sharing (n,h) panels land on the same XCD (L2 locality)
__global__ __launch_bounds__(512) void attn_kernel(float* __restrict__ ws,
                                                   const int* __restrict__ mask,
                                                   float* __restrict__ d_out) {
    __shared__ __align__(16) float S[16][516];     // 33024 B
    __shared__ __align__(16) float red[4][16][17]; // 4352 B

    const unsigned short* qu_b = (const unsigned short*)(ws + WS_QU);
    const unsigned short* qv_b = (const unsigned short*)(ws + WS_QV);
    const unsigned short* k_b  = (const unsigned short*)(ws + WS_KB);
    const unsigned short* vT_b = (const unsigned short*)(ws + WS_VT);
    const unsigned short* relb = (const unsigned short*)(ws + WS_RELB);
    unsigned short* ohb = (unsigned short*)(ws + WS_OH);
    float* attn = d_out + 4194304;                 // [N][H][Q][K]

    int bid = blockIdx.x;                          // 4096 = 128 nh x 32 q-tiles
    int swz = (bid & 7) * 512 + (bid >> 3);        // bijective XCD swizzle
    int nh = swz >> 5;
    int n  = nh >> 3, h = nh & 7;
    int q0 = (swz & 31) * 16;

    int tid  = threadIdx.x;
    int w    = tid >> 6, lane = tid & 63;
    int fr   = lane & 15, fg = lane >> 4;

    // q fragments (A-row = fr)
    bf16x8 quf[2], qvf[2];
    {
        long qb = ((long)(nh * 512 + q0 + fr)) * 64;
#pragma unroll
        for (int s = 0; s < 2; ++s) {
            quf[s] = *(const bf16x8*)&qu_b[qb + (fg + 4 * s) * 8];
            qvf[s] = *(const bf16x8*)&qv_b[qb + (fg + 4 * s) * 8];
        }
    }

    // ---- content: S[r][k] = (q+u).k ; wave w covers k-strip [w*64, w*64+64)
    {
        const unsigned short* kbase = k_b + (long)nh * 512 * 64;
        f32x4 cacc[4] = {};
#pragma unroll
        for (int t = 0; t < 4; ++t) {
            int kcol = w * 64 + t * 16 + fr;
            const unsigned short* kp = kbase + (long)kcol * 64;
            bf16x8 b0 = *(const bf16x8*)&kp[fg * 8];
            bf16x8 b1 = *(const bf16x8*)&kp[(fg + 4) * 8];
            cacc[t] = MFMA16(quf[0], b0, cacc[t], 0, 0, 0);
            cacc[t] = MFMA16(quf[1], b1, cacc[t], 0, 0, 0);
        }
#pragma unroll
        for (int t = 0; t < 4; ++t)
#pragma unroll
            for (int i = 0; i < 4; ++i)
                S[fg * 4 + i][w * 64 + t * 16 + fr] = cacc[t][i];
    }
    __syncthreads();

    // ---- position: S[r][k] += (q+v).rel[j], k = r + 511 - jj, j = q0+1+jj
    {
        const unsigned short* rbase = relb + (long)h * 1024 * 64;
        for (int jt = w; jt < 33; jt += 8) {
            int jj = jt * 16 + fr;
            int j = q0 + 1 + jj; if (j > 1023) j = 1023;  // clamped -> k<0, discarded
            const unsigned short* rp = rbase + (long)j * 64;
            bf16x8 b0 = *(const bf16x8*)&rp[fg * 8];
            bf16x8 b1 = *(const bf16x8*)&rp[(fg + 4) * 8];
            f32x4 acc = {0.f, 0.f, 0.f, 0.f};
            acc = MFMA16(qvf[0], b0, acc, 0, 0, 0);
            acc = MFMA16(qvf[1], b1, acc, 0, 0, 0);
#pragma unroll
            for (int i = 0; i < 4; ++i) {
                int r = fg * 4 + i;
                int k = r + 511 - jj;
                if ((unsigned)k < 512u) S[r][k] += acc[i];
            }
        }
    }
    __syncthreads();

    // ---- mask + scale + softmax (vectorized: lane owns k in [lane*8, lane*8+8))
    for (int rr = 0; rr < 2; ++rr) {
        int r = w * 2 + rr;
        const int* mrow = mask + ((long)(n * 512 + q0 + r)) * 512;
        f32x4 s0 = *(const f32x4*)&S[r][lane * 8];
        f32x4 s1 = *(const f32x4*)&S[r][lane * 8 + 4];
        int4 m0 = *(const int4*)&mrow[lane * 8];
        int4 m1 = *(const int4*)&mrow[lane * 8 + 4];
        float lg[8];
        lg[0] = (m0.x == 0) ? -1.25e19f : s0[0] * 0.125f;
        lg[1] = (m0.y == 0) ? -1.25e19f : s0[1] * 0.125f;
        lg[2] = (m0.z == 0) ? -1.25e19f : s0[2] * 0.125f;
        lg[3] = (m0.w == 0) ? -1.25e19f : s0[3] * 0.125f;
        lg[4] = (m1.x == 0) ? -1.25e19f : s1[0] * 0.125f;
        lg[5] = (m1.y == 0) ? -1.25e19f : s1[1] * 0.125f;
        lg[6] = (m1.z == 0) ? -1.25e19f : s1[2] * 0.125f;
        lg[7] = (m1.w == 0) ? -1.25e19f : s1[3] * 0.125f;
        float mx = lg[0];
#pragma unroll
        for (int j = 1; j < 8; ++j) mx = fmaxf(mx, lg[j]);
        for (int o = 32; o > 0; o >>= 1) mx = fmaxf(mx, __shfl_xor(mx, o, 64));
        float sum = 0.f;
#pragma unroll
        for (int j = 0; j < 8; ++j) { lg[j] = __expf(lg[j] - mx); sum += lg[j]; }
        for (int o = 32; o > 0; o >>= 1) sum += __shfl_xor(sum, o, 64);
        float inv = 1.0f / sum;
        f32x4 p0 = {lg[0] * inv, lg[1] * inv, lg[2] * inv, lg[3] * inv};
        f32x4 p1 = {lg[4] * inv, lg[5] * inv, lg[6] * inv, lg[7] * inv};
        *(f32x4*)&S[r][lane * 8]     = p0;
        *(f32x4*)&S[r][lane * 8 + 4] = p1;
        float* arow = attn + ((long)(nh * 512 + q0 + r)) * 512;
        *(f32x4*)&arow[lane * 8]     = p0;
        *(f32x4*)&arow[lane * 8 + 4] = p1;
    }
    __syncthreads();

    // ---- PV: oh[q][d] = P.v ; wave -> (d-tile w&3, k-half w>>2); LDS reduce
    {
        int dt = w & 3, kh = w >> 2;
        const unsigned short* vp0 =
            vT_b + ((long)(nh * 64 + dt * 16 + fr)) * 512 + kh * 256;
        f32x4 oacc = {0.f, 0.f, 0.f, 0.f};
#pragma unroll
        for (int kk = 0; kk < 8; ++kk) {
            const float* sp = &S[fr][kh * 256 + kk * 32 + fg * 8];
            f32x4 a = *(const f32x4*)sp;
            f32x4 b = *(const f32x4*)(sp + 4);
            bf16x8 pk = pack8(a, b);
            bf16x8 bf = *(const bf16x8*)&vp0[kk * 32 + fg * 8];
            oacc = MFMA16(pk, bf, oacc, 0, 0, 0);
        }
        if (kh == 1) {
#pragma unroll
            for (int i = 0; i < 4; ++i) red[dt][fg * 4 + i][fr] = oacc[i];
        }
        __syncthreads();
        if (kh == 0) {
#pragma unroll
            for (int i = 0; i < 4; ++i) {
                float o = oacc[i] + red[dt][fg * 4 + i][fr];
                ohb[((long)(n * 512 + q0 + fg * 4 + i)) * 512 +
                    h * 64 + dt * 16 + fr] = f2bf(o);
            }
        }
    }
}

// ----------------------- out = oh @ Wo^T + bo  (bf16 MFMA, f32 epilogue)
__global__ __launch_bounds__(256) void wo_kernel(const float* __restrict__ ws,
                                                 const float* __restrict__ Wo,
                                                 const float* __restrict__ bo,
                                                 float* __restrict__ d_out) {
    __shared__ __align__(16) unsigned short At[128][64];   // 16 KB
    __shared__ __align__(16) unsigned short Bt[64][64];    // 8 KB
    const unsigned short* ohb = (const unsigned short*)(ws + WS_OH);
    int bm = blockIdx.x >> 3, bn = blockIdx.x & 7;
    int tid = threadIdx.x;
    int w = tid >> 6, lane = tid & 63;
    int fr = lane & 15, fg = lane >> 4;
    f32x4 acc[2][4] = {};
    for (int kk = 0; kk < 512; kk += 64) {
        __syncthreads();
        for (int p = 0; p < 4; ++p) {
            int idx = tid + 256 * p;       // 0..1023
            int row = idx >> 3, slot = idx & 7;
            *(bf16x8*)&At[row][((slot ^ (row & 7))) * 8] =
                *(const bf16x8*)&ohb[(long)(bm * 128 + row) * 512 + kk + slot * 8];
        }
        for (int p = 0; p < 2; ++p) {
            int idx = tid + 256 * p;       // 0..511
            int row = idx >> 3, slot = idx & 7;
            const float* g = &Wo[(bn * 64 + row) * 512 + kk + slot * 8];
            float4 a = *(const float4*)g;
            float4 b = *(const float4*)(g + 4);
            ushort8v pk;
            pk[0] = f2bf(a.x); pk[1] = f2bf(a.y); pk[2] = f2bf(a.z); pk[3] = f2bf(a.w);
            pk[4] = f2bf(b.x); pk[5] = f2bf(b.y); pk[6] = f2bf(b.z); pk[7] = f2bf(b.w);
            *(ushort8v*)&Bt[row][((slot ^ (row & 7))) * 8] = pk;
        }
        __syncthreads();
        bf16x8 af[2][2], bfr[4][2];
#pragma unroll
        for (int t = 0; t < 2; ++t) {
            int ar = w * 32 + t * 16 + fr;
#pragma unroll
            for (int s = 0; s < 2; ++s)
                af[t][s] = *(const bf16x8*)&At[ar][((fg + s * 4) ^ (ar & 7)) * 8];
        }
#pragma unroll
        for (int c = 0; c < 4; ++c) {
            int br = c * 16 + fr;
#pragma unroll
            for (int s = 0; s < 2; ++s)
                bfr[c][s] = *(const bf16x8*)&Bt[br][((fg + s * 4) ^ (br & 7)) * 8];
        }
#pragma unroll
        for (int t = 0; t < 2; ++t)
#pragma unroll
            for (int c = 0; c < 4; ++c)
#pragma unroll
                for (int s = 0; s < 2; ++s)
                    acc[t][c] = MFMA16(af[t][s], bfr[c][s], acc[t][c], 0, 0, 0);
    }
#pragma unroll
    for (int t = 0; t < 2; ++t)
#pragma unroll
        for (int c = 0; c < 4; ++c) {
            int col = bn * 64 + c * 16 + fr;
            float b = bo[col];
#pragma unroll
            for (int i = 0; i < 4; ++i) {
                int row = bm * 128 + w * 32 + t * 16 + fg * 4 + i;
                d_out[(long)row * 512 + col] = acc[t][c][i] + b;
            }
        }
}

extern "C" void kernel_launch(void* const* d_in, const int* in_sizes, int n_in,
                              void* d_out, int out_size, void* d_ws, size_t ws_size,
                              hipStream_t stream) {
    const float* values = (const float*)d_in[0];
    const float* keys   = (const float*)d_in[1];
    const float* query  = (const float*)d_in[2];
    const int*   mask   = (const int*)d_in[3];
    const float* Wv     = (const float*)d_in[4];
    const float* Wk     = (const float*)d_in[5];
    const float* Wq     = (const float*)d_in[6];
    const float* Wr     = (const float*)d_in[7];
    const float* u_bias = (const float*)d_in[8];
    const float* v_bias = (const float*)d_in[9];
    const float* Wo     = (const float*)d_in[10];
    const float* bo     = (const float*)d_in[11];
    float* out = (float*)d_out;
    float* ws  = (float*)d_ws;

    unsigned short* peb  = (unsigned short*)(ws + WS_PEB);
    unsigned short* relb = (unsigned short*)(ws + WS_RELB);

    hipLaunchKernelGGL(pe_kernel,   dim3(1024),  dim3(256), 0, stream, peb);
    hipLaunchKernelGGL(rel_kernel,  dim3(128),   dim3(256), 0, stream, peb, Wr, relb);
    hipLaunchKernelGGL(proj_kernel, dim3(256),   dim3(256), 0, stream,
                       query, keys, values, Wq, Wk, Wv, u_bias, v_bias, ws);
    hipLaunchKernelGGL(attn_kernel, dim3(4096),  dim3(512), 0, stream, ws, mask, out);
    hipLaunchKernelGGL(wo_kernel,   dim3(512),   dim3(256), 0, stream, ws, Wo, bo, out);
}

// Round 7
// 146.366 us; speedup vs baseline: 1.1840x; 1.1840x over previous
//
#include <hip/hip_runtime.h>
#include <math.h>

// Problem constants
#define NB     16
#define HEADS  8
#define HD     64
#define EMBED  512
#define QL     512
#define KL     512

// ws layout (float-unit offsets)
#define WS_QU   0           // bf16 [16][8][512][64]
#define WS_QV   2097152     // bf16 [16][8][512][64]
#define WS_KB   4194304     // bf16 [16][8][512][64]
#define WS_VT   6291456     // bf16 [16][8][64][512]  (v transposed)
#define WS_PEB  8388608     // bf16 [1024][512]
#define WS_RELB 8912896     // bf16 [8][1024][64]
#define WS_OH   9175040     // bf16 [16][512][512]

typedef __attribute__((ext_vector_type(8))) short bf16x8;
typedef __attribute__((ext_vector_type(4))) float f32x4;
typedef __attribute__((ext_vector_type(8))) unsigned short ushort8v;
typedef __attribute__((ext_vector_type(4))) unsigned short ushort4v;

#define MFMA16 __builtin_amdgcn_mfma_f32_16x16x32_bf16

static __device__ __forceinline__ unsigned short f2bf(float x) {
    unsigned u = __builtin_bit_cast(unsigned, x);
    u += 0x7fffu + ((u >> 16) & 1u);      // round-to-nearest-even
    return (unsigned short)(u >> 16);
}

// pack 8 f32 -> bf16x8 via v_cvt_pk_bf16_f32 (RNE), 4 instructions
static __device__ __forceinline__ bf16x8 pack8(f32x4 a, f32x4 b) {
    union { bf16x8 v; unsigned u[4]; } r;
    asm("v_cvt_pk_bf16_f32 %0, %1, %2" : "=v"(r.u[0]) : "v"(a[0]), "v"(a[1]));
    asm("v_cvt_pk_bf16_f32 %0, %1, %2" : "=v"(r.u[1]) : "v"(a[2]), "v"(a[3]));
    asm("v_cvt_pk_bf16_f32 %0, %1, %2" : "=v"(r.u[2]) : "v"(b[0]), "v"(b[1]));
    asm("v_cvt_pk_bf16_f32 %0, %1, %2" : "=v"(r.u[3]) : "v"(b[2]), "v"(b[3]));
    return r.v;
}

// ---------------------------------------------------------------- PE table (bf16)
__global__ void pe_kernel(unsigned short* __restrict__ peb) {
    int j = blockIdx.x;        // 0..1023
    int i = threadIdx.x;       // 0..255
    float invf = exp2f(-(float)i * (13.287712379549449f / 256.0f));
    float ang  = (float)j * invf;
    peb[j * 512 + i]       = f2bf(sinf(ang));
    peb[j * 512 + 256 + i] = f2bf(cosf(ang));
}

// ----------------------------------------- relb = bf16(PE @ Wr^T), MFMA
__global__ __launch_bounds__(256) void rel_kernel(const unsigned short* __restrict__ peb,
                                                  const float* __restrict__ Wr,
                                                  unsigned short* __restrict__ relb) {
    __shared__ __align__(16) unsigned short At[64][64];
    __shared__ __align__(16) unsigned short Bt[64][64];
    int bm = blockIdx.x >> 3, bn = blockIdx.x & 7;
    int tid = threadIdx.x;
    int w = tid >> 6, lane = tid & 63;
    int fr = lane & 15, fg = lane >> 4;
    f32x4 acc[4] = {};
    for (int kk = 0; kk < 512; kk += 64) {
        __syncthreads();
        for (int p = 0; p < 2; ++p) {
            int idx = tid + 256 * p;              // 0..511
            int row = idx >> 3, slot = idx & 7;
            *(bf16x8*)&At[row][((slot ^ (row & 7))) * 8] =
                *(const bf16x8*)&peb[(bm * 64 + row) * 512 + kk + slot * 8];
        }
        for (int p = 0; p < 4; ++p) {
            int idx = tid + 256 * p;              // 0..1023 = 64 rows x 16 float4
            int row = idx >> 4, c4 = idx & 15;
            float4 v = *(const float4*)&Wr[(bn * 64 + row) * 512 + kk + c4 * 4];
            ushort4v pk;
            pk[0] = f2bf(v.x); pk[1] = f2bf(v.y); pk[2] = f2bf(v.z); pk[3] = f2bf(v.w);
            int slot = c4 >> 1, rem = (c4 & 1) * 4;
            *(ushort4v*)&Bt[row][((slot ^ (row & 7))) * 8 + rem] = pk;
        }
        __syncthreads();
        bf16x8 af[2];
        int ar = w * 16 + fr;
#pragma unroll
        for (int s = 0; s < 2; ++s)
            af[s] = *(const bf16x8*)&At[ar][((fg + 4 * s) ^ (ar & 7)) * 8];
#pragma unroll
        for (int c = 0; c < 4; ++c) {
            int br = c * 16 + fr;
#pragma unroll
            for (int s = 0; s < 2; ++s) {
                bf16x8 bf = *(const bf16x8*)&Bt[br][((fg + 4 * s) ^ (br & 7)) * 8];
                acc[c] = MFMA16(af[s], bf, acc[c], 0, 0, 0);
            }
        }
    }
#pragma unroll
    for (int c = 0; c < 4; ++c)
#pragma unroll
        for (int i = 0; i < 4; ++i)
            relb[(bn * 1024 + bm * 64 + w * 16 + fg * 4 + i) * 64 + c * 16 + fr] =
                f2bf(acc[c][i]);
}

// ------------------------------------------------- q/k/v head projections, MFMA
__global__ __launch_bounds__(256) void proj_kernel(const float* __restrict__ query,
                                                   const float* __restrict__ keys,
                                                   const float* __restrict__ values,
                                                   const float* __restrict__ Wq,
                                                   const float* __restrict__ Wk,
                                                   const float* __restrict__ Wv,
                                                   const float* __restrict__ u_bias,
                                                   const float* __restrict__ v_bias,
                                                   float* __restrict__ ws) {
    __shared__ __align__(16) unsigned short inb[32][512];     // 32 KB
    __shared__ __align__(16) unsigned short Wb[3][64][64];    // 24 KB
    __shared__ __align__(16) unsigned short vtile[4][64][36]; // 18 KB
    int n = blockIdx.x >> 4, t0 = (blockIdx.x & 15) * 32;
    int tid = threadIdx.x;
    int w = tid >> 6, lane = tid & 63;
    int fr = lane & 15, fg = lane >> 4;

    for (int p = 0; p < 3; ++p) {
        const float* Wp = (p == 0) ? Wq : (p == 1) ? Wk : Wv;
        for (int it = 0; it < 4; ++it) {
            int idx = tid + 256 * it;            // 0..1023 = 64 rows x 16 float4
            int row = idx >> 4, c4 = idx & 15;
            float4 v = *(const float4*)&Wp[row * 64 + c4 * 4];
            ushort4v pk;
            pk[0] = f2bf(v.x); pk[1] = f2bf(v.y); pk[2] = f2bf(v.z); pk[3] = f2bf(v.w);
            int slot = c4 >> 1, rem = (c4 & 1) * 4;
            *(ushort4v*)&Wb[p][row][((slot ^ (row & 7))) * 8 + rem] = pk;
        }
    }
    unsigned short* qu_b = (unsigned short*)(ws + WS_QU);
    unsigned short* qv_b = (unsigned short*)(ws + WS_QV);
    unsigned short* k_b  = (unsigned short*)(ws + WS_KB);
    unsigned short* vT_b = (unsigned short*)(ws + WS_VT);

    for (int p = 0; p < 3; ++p) {
        const float* src = (p == 0) ? query : (p == 1) ? keys : values;
        __syncthreads();                         // Wb ready / inb WAR
        for (int it = 0; it < 16; ++it) {
            int idx = tid + 256 * it;            // 0..4095 = 32 rows x 128 float4
            int row = idx >> 7, c4 = idx & 127;
            float4 v = *(const float4*)&src[((long)(n * 512 + t0 + row)) * 512 + c4 * 4];
            ushort4v pk;
            pk[0] = f2bf(v.x); pk[1] = f2bf(v.y); pk[2] = f2bf(v.z); pk[3] = f2bf(v.w);
            int slot = c4 >> 1, rem = (c4 & 1) * 4;
            *(ushort4v*)&inb[row][((slot ^ (row & 7))) * 8 + rem] = pk;
        }
        __syncthreads();
        for (int hh = 0; hh < 2; ++hh) {
            int h = w * 2 + hh, nh = n * 8 + h;
            bf16x8 af[2][2];
#pragma unroll
            for (int tt = 0; tt < 2; ++tt) {
                int ar = tt * 16 + fr;
#pragma unroll
                for (int s = 0; s < 2; ++s)
                    af[tt][s] = *(const bf16x8*)&inb[ar][(h * 8 + ((fg + 4 * s) ^ (ar & 7))) * 8];
            }
            f32x4 acc[2][4] = {};
#pragma unroll
            for (int dt = 0; dt < 4; ++dt) {
                int br = dt * 16 + fr;
                bf16x8 bf[2];
#pragma unroll
                for (int s = 0; s < 2; ++s)
                    bf[s] = *(const bf16x8*)&Wb[p][br][((fg + 4 * s) ^ (br & 7)) * 8];
#pragma unroll
                for (int tt = 0; tt < 2; ++tt)
#pragma unroll
                    for (int s = 0; s < 2; ++s)
                        acc[tt][dt] = MFMA16(af[tt][s], bf[s], acc[tt][dt], 0, 0, 0);
            }
            if (p == 0) {
#pragma unroll
                for (int dt = 0; dt < 4; ++dt) {
                    float ub = u_bias[h * 64 + dt * 16 + fr];
                    float vb = v_bias[h * 64 + dt * 16 + fr];
#pragma unroll
                    for (int tt = 0; tt < 2; ++tt)
#pragma unroll
                        for (int i = 0; i < 4; ++i) {
                            long o = ((long)(nh * 512 + t0 + tt * 16 + fg * 4 + i)) * 64 +
                                     dt * 16 + fr;
                            qu_b[o] = f2bf(acc[tt][dt][i] + ub);
                            qv_b[o] = f2bf(acc[tt][dt][i] + vb);
                        }
                }
            } else if (p == 1) {
#pragma unroll
                for (int dt = 0; dt < 4; ++dt)
#pragma unroll
                    for (int tt = 0; tt < 2; ++tt)
#pragma unroll
                        for (int i = 0; i < 4; ++i)
                            k_b[((long)(nh * 512 + t0 + tt * 16 + fg * 4 + i)) * 64 +
                                dt * 16 + fr] = f2bf(acc[tt][dt][i]);
            } else {
                // transpose via per-wave LDS tile, then coalesced vT store
#pragma unroll
                for (int dt = 0; dt < 4; ++dt)
#pragma unroll
                    for (int tt = 0; tt < 2; ++tt)
#pragma unroll
                        for (int i = 0; i < 4; ++i)
                            vtile[w][dt * 16 + fr][tt * 16 + fg * 4 + i] =
                                f2bf(acc[tt][dt][i]);
                __syncthreads();
#pragma unroll
                for (int dg = 0; dg < 8; ++dg) {
                    int d = dg * 8 + (lane >> 3), tq = lane & 7;
                    *(ushort4v*)&vT_b[((long)(nh * 64 + d)) * 512 + t0 + tq * 4] =
                        *(const ushort4v*)&vtile[w][d][tq * 4];
                }
                __syncthreads();
            }
        }
    }
}

// ------------------------------------------- fused MFMA scores+softmax+PV
// one block per (n, h, 128-row q-group); loops 4 q-tiles of 32 rows.
// K-strip and V-block are REGISTER-RESIDENT per wave, reused across tiles.
// grid 512 = 128 nh x 4 q-groups; 512 threads = 8 waves; 2 blocks/CU.
__global__ __launch_bounds__(512) void attn_kernel(float* __restrict__ ws,
                                                   const int* __restrict__ mask,
                                                   float* __restrict__ d_out) {
    __shared__ __align__(16) float S[32][516];     // 66048 B
    __shared__ __align__(16) float red[4][32][17]; // 8704 B

    const unsigned short* qu_b = (const unsigned short*)(ws + WS_QU);
    const unsigned short* qv_b = (const unsigned short*)(ws + WS_QV);
    const unsigned short* k_b  = (const unsigned short*)(ws + WS_KB);
    const unsigned short* vT_b = (const unsigned short*)(ws + WS_VT);
    const unsigned short* relb = (const unsigned short*)(ws + WS_RELB);
    unsigned short* ohb = (unsigned short*)(ws + WS_OH);
    float* attn = d_out + 4194304;                 // [N][H][Q][K]

    int bid = blockIdx.x;                          // 512 blocks
    int swz = (bid & 7) * 64 + (bid >> 3);         // bijective XCD swizzle
    int nh = swz >> 2, qb = swz & 3;
    int n  = nh >> 3, h = nh & 7;

    int tid  = threadIdx.x;
    int w    = tid >> 6, lane = tid & 63;
    int fr   = lane & 15, fg = lane >> 4;

    // persistent K-strip: wave w owns k in [w*64, w*64+64)
    const unsigned short* kbase = k_b + (long)nh * 512 * 64;
    bf16x8 kreg[4][2];
#pragma unroll
    for (int t = 0; t < 4; ++t) {
        const unsigned short* kp = kbase + (long)(w * 64 + t * 16 + fr) * 64;
        kreg[t][0] = *(const bf16x8*)&kp[fg * 8];
        kreg[t][1] = *(const bf16x8*)&kp[(fg + 4) * 8];
    }
    // persistent V-block: wave -> (d-tile dt, k-half kh)
    int dt = w & 3, kh = w >> 2;
    const unsigned short* vp0 = vT_b + ((long)(nh * 64 + dt * 16 + fr)) * 512 + kh * 256;
    bf16x8 vreg[8];
#pragma unroll
    for (int kk = 0; kk < 8; ++kk)
        vreg[kk] = *(const bf16x8*)&vp0[kk * 32 + fg * 8];

    const unsigned short* rbase = relb + (long)h * 1024 * 64;

    for (int ti = 0; ti < 4; ++ti) {
        int q0 = qb * 128 + ti * 32;

        // ---- content: S[r][k] = (q+u).k  (K from registers, zero loads)
#pragma unroll
        for (int qt = 0; qt < 2; ++qt) {
            long qa = ((long)(nh * 512 + q0 + qt * 16 + fr)) * 64;
            bf16x8 a0 = *(const bf16x8*)&qu_b[qa + fg * 8];
            bf16x8 a1 = *(const bf16x8*)&qu_b[qa + (fg + 4) * 8];
#pragma unroll
            for (int t = 0; t < 4; ++t) {
                f32x4 acc = {0.f, 0.f, 0.f, 0.f};
                acc = MFMA16(a0, kreg[t][0], acc, 0, 0, 0);
                acc = MFMA16(a1, kreg[t][1], acc, 0, 0, 0);
                int kcol = w * 64 + t * 16 + fr;
#pragma unroll
                for (int i = 0; i < 4; ++i)
                    S[qt * 16 + fg * 4 + i][kcol] = acc[i];
            }
        }
        __syncthreads();

        // ---- position: S[r][k] += (q+v).rel[j], k = r + 511 - jj, j = q0+1+jj
        {
            bf16x8 qvf[2][2];
#pragma unroll
            for (int qt = 0; qt < 2; ++qt) {
                long qa = ((long)(nh * 512 + q0 + qt * 16 + fr)) * 64;
                qvf[qt][0] = *(const bf16x8*)&qv_b[qa + fg * 8];
                qvf[qt][1] = *(const bf16x8*)&qv_b[qa + (fg + 4) * 8];
            }
            for (int jt = w; jt < 34; jt += 8) {
                int jj = jt * 16 + fr;
                int j = q0 + 1 + jj;     // may reach 1024: OOB row lands in ws (WS_OH),
                                         // its k = r-32 < 0 -> always discarded below
                const unsigned short* rp = rbase + (long)j * 64;
                bf16x8 b0 = *(const bf16x8*)&rp[fg * 8];
                bf16x8 b1 = *(const bf16x8*)&rp[(fg + 4) * 8];
#pragma unroll
                for (int qt = 0; qt < 2; ++qt) {
                    f32x4 acc = {0.f, 0.f, 0.f, 0.f};
                    acc = MFMA16(qvf[qt][0], b0, acc, 0, 0, 0);
                    acc = MFMA16(qvf[qt][1], b1, acc, 0, 0, 0);
#pragma unroll
                    for (int i = 0; i < 4; ++i) {
                        int r = qt * 16 + fg * 4 + i;
                        int k = r + 511 - jj;
                        if ((unsigned)k < 512u) S[r][k] += acc[i];
                    }
                }
            }
        }
        __syncthreads();

        // ---- mask + scale + softmax (scalar k = lane+64j: conflict-free LDS)
        for (int rr = 0; rr < 4; ++rr) {
            int r = w * 4 + rr;
            const int* mrow = mask + ((long)(n * 512 + q0 + r)) * 512;
            float lg[8];
            float mx = -3.0e38f;
#pragma unroll
            for (int j = 0; j < 8; ++j) {
                int k = lane + 64 * j;
                float s = S[r][k];
                int m = mrow[k];
                float l = (m == 0) ? -1.25e19f : s * 0.125f;
                lg[j] = l;
                mx = fmaxf(mx, l);
            }
            for (int o = 32; o > 0; o >>= 1) mx = fmaxf(mx, __shfl_xor(mx, o, 64));
            float sum = 0.f;
#pragma unroll
            for (int j = 0; j < 8; ++j) { lg[j] = __expf(lg[j] - mx); sum += lg[j]; }
            for (int o = 32; o > 0; o >>= 1) sum += __shfl_xor(sum, o, 64);
            float inv = 1.0f / sum;
            float* arow = attn + ((long)(nh * 512 + q0 + r)) * 512;
#pragma unroll
            for (int j = 0; j < 8; ++j) {
                int k = lane + 64 * j;
                float p = lg[j] * inv;
                S[r][k] = p;
                arow[k] = p;
            }
        }
        __syncthreads();

        // ---- PV: oh[q][d] = P.v  (V from registers, zero loads)
        {
            f32x4 oacc[2] = {{0.f,0.f,0.f,0.f},{0.f,0.f,0.f,0.f}};
#pragma unroll
            for (int kk = 0; kk < 8; ++kk) {
#pragma unroll
                for (int qt = 0; qt < 2; ++qt) {
                    const float* sp = &S[qt * 16 + fr][kh * 256 + kk * 32 + fg * 8];
                    f32x4 a = *(const f32x4*)sp;
                    f32x4 b = *(const f32x4*)(sp + 4);
                    bf16x8 pk = pack8(a, b);
                    oacc[qt] = MFMA16(pk, vreg[kk], oacc[qt], 0, 0, 0);
                }
            }
            if (kh == 1) {
#pragma unroll
                for (int qt = 0; qt < 2; ++qt)
#pragma unroll
                    for (int i = 0; i < 4; ++i)
                        red[dt][qt * 16 + fg * 4 + i][fr] = oacc[qt][i];
            }
            __syncthreads();
            if (kh == 0) {
#pragma unroll
                for (int qt = 0; qt < 2; ++qt)
#pragma unroll
                    for (int i = 0; i < 4; ++i) {
                        float o = oacc[qt][i] + red[dt][qt * 16 + fg * 4 + i][fr];
                        ohb[((long)(n * 512 + q0 + qt * 16 + fg * 4 + i)) * 512 +
                            h * 64 + dt * 16 + fr] = f2bf(o);
                    }
            }
        }
        __syncthreads();   // S + red reusable for next tile
    }
}

// ----------------------- out = oh @ Wo^T + bo  (bf16 MFMA, f32 epilogue)
__global__ __launch_bounds__(256) void wo_kernel(const float* __restrict__ ws,
                                                 const float* __restrict__ Wo,
                                                 const float* __restrict__ bo,
                                                 float* __restrict__ d_out) {
    __shared__ __align__(16) unsigned short At[128][64];   // 16 KB
    __shared__ __align__(16) unsigned short Bt[64][64];    // 8 KB
    const unsigned short* ohb = (const unsigned short*)(ws + WS_OH);
    int bm = blockIdx.x >> 3, bn = blockIdx.x & 7;
    int tid = threadIdx.x;
    int w = tid >> 6, lane = tid & 63;
    int fr = lane & 15, fg = lane >> 4;
    f32x4 acc[2][4] = {};
    for (int kk = 0; kk < 512; kk += 64) {
        __syncthreads();
        for (int p = 0; p < 4; ++p) {
            int idx = tid + 256 * p;       // 0..1023
            int row = idx >> 3, slot = idx & 7;
            *(bf16x8*)&At[row][((slot ^ (row & 7))) * 8] =
                *(const bf16x8*)&ohb[(long)(bm * 128 + row) * 512 + kk + slot * 8];
        }
        for (int p = 0; p < 2; ++p) {
            int idx = tid + 256 * p;       // 0..511
            int row = idx >> 3, slot = idx & 7;
            const float* g = &Wo[(bn * 64 + row) * 512 + kk + slot * 8];
            float4 a = *(const float4*)g;
            float4 b = *(const float4*)(g + 4);
            ushort8v pk;
            pk[0] = f2bf(a.x); pk[1] = f2bf(a.y); pk[2] = f2bf(a.z); pk[3] = f2bf(a.w);
            pk[4] = f2bf(b.x); pk[5] = f2bf(b.y); pk[6] = f2bf(b.z); pk[7] = f2bf(b.w);
            *(ushort8v*)&Bt[row][((slot ^ (row & 7))) * 8] = pk;
        }
        __syncthreads();
        bf16x8 af[2][2], bfr[4][2];
#pragma unroll
        for (int t = 0; t < 2; ++t) {
            int ar = w * 32 + t * 16 + fr;
#pragma unroll
            for (int s = 0; s < 2; ++s)
                af[t][s] = *(const bf16x8*)&At[ar][((fg + s * 4) ^ (ar & 7)) * 8];
        }
#pragma unroll
        for (int c = 0; c < 4; ++c) {
            int br = c * 16 + fr;
#pragma unroll
            for (int s = 0; s < 2; ++s)
                bfr[c][s] = *(const bf16x8*)&Bt[br][((fg + s * 4) ^ (br & 7)) * 8];
        }
#pragma unroll
        for (int t = 0; t < 2; ++t)
#pragma unroll
            for (int c = 0; c < 4; ++c)
#pragma unroll
                for (int s = 0; s < 2; ++s)
                    acc[t][c] = MFMA16(af[t][s], bfr[c][s], acc[t][c], 0, 0, 0);
    }
#pragma unroll
    for (int t = 0; t < 2; ++t)
#pragma unroll
        for (int c = 0; c < 4; ++c) {
            int col = bn * 64 + c * 16 + fr;
            float b = bo[col];
#pragma unroll
            for (int i = 0; i < 4; ++i) {
                int row = bm * 128 + w * 32 + t * 16 + fg * 4 + i;
                d_out[(long)row * 512 + col] = acc[t][c][i] + b;
            }
        }
}

extern "C" void kernel_launch(void* const* d_in, const int* in_sizes, int n_in,
                              void* d_out, int out_size, void* d_ws, size_t ws_size,
                              hipStream_t stream) {
    const float* values = (const float*)d_in[0];
    const float* keys   = (const float*)d_in[1];
    const float* query  = (const float*)d_in[2];
    const int*   mask   = (const int*)d_in[3];
    const float* Wv     = (const float*)d_in[4];
    const float* Wk     = (const float*)d_in[5];
    const float* Wq     = (const float*)d_in[6];
    const float* Wr     = (const float*)d_in[7];
    const float* u_bias = (const float*)d_in[8];
    const float* v_bias = (const float*)d_in[9];
    const float* Wo     = (const float*)d_in[10];
    const float* bo     = (const float*)d_in[11];
    float* out = (float*)d_out;
    float* ws  = (float*)d_ws;

    unsigned short* peb  = (unsigned short*)(ws + WS_PEB);
    unsigned short* relb = (unsigned short*)(ws + WS_RELB);

    hipLaunchKernelGGL(pe_kernel,   dim3(1024),  dim3(256), 0, stream, peb);
    hipLaunchKernelGGL(rel_kernel,  dim3(128),   dim3(256), 0, stream, peb, Wr, relb);
    hipLaunchKernelGGL(proj_kernel, dim3(256),   dim3(256), 0, stream,
                       query, keys, values, Wq, Wk, Wv, u_bias, v_bias, ws);
    hipLaunchKernelGGL(attn_kernel, dim3(512),   dim3(512), 0, stream, ws, mask, out);
    hipLaunchKernelGGL(wo_kernel,   dim3(512),   dim3(256), 0, stream, ws, Wo, bo, out);
}